// Round 6
// baseline (228.561 us; speedup 1.0000x reference)
//
#include <hip/hip_runtime.h>
#include <math.h>

#define Vdim 13
#define HW 20480               // 128*160
#define UV 169
#define NPIX (8 * HW)          // 163840
#define NPL 43                 // planes per group: 43,43,43,40(+3 pad)

// Register-resident single pass, float4 pixels: 4 threads... rather,
// wave = 4 plane-groups x 16 lanes; each lane owns 4 consecutive pixels
// (float4) and 43 planes -> every 16-lane group load is 256B contiguous,
// wave-load = 1KB (vs round-5's 4x64B islands at 3.5MB stride, which ran
// at 1.66 TB/s logical). 172 pinned VGPR values; launch_bounds(256,2).
__global__ __launch_bounds__(256, 2) void flow_regression_kernel(
    const float* __restrict__ x, float* __restrict__ out) {
    int t    = threadIdx.x;
    int wave = t >> 6;
    int lane = t & 63;
    int q    = lane >> 4;                       // plane group 0..3
    int pix0 = blockIdx.x * 256 + wave * 64 + (lane & 15) * 4;
    int b    = pix0 / HW;                       // uniform per block (HW%256==0)
    int hw   = pix0 - b * HW;
    int base_pl = q * NPL;                      // 0,43,86,129

    const float* gp = x + (size_t)b * UV * HW + hw;

    // ---- Load 43 planes x 4 pixels (float4: 256B contiguous per group) ----
    float va[4][NPL];
    #pragma unroll
    for (int i = 0; i < 40; ++i) {
        const float4 v4 = *(const float4*)(gp + (size_t)(base_pl + i) * HW);
        va[0][i] = v4.x; va[1][i] = v4.y; va[2][i] = v4.z; va[3][i] = v4.w;
    }
    #pragma unroll
    for (int i = 40; i < NPL; ++i) {            // only q==3 pads (pl 169..171)
        int pl   = base_pl + i;
        bool pad = pl >= UV;
        const float4 v4 = *(const float4*)(gp + (size_t)(pad ? (UV - 1) : pl) * HW);
        va[0][i] = pad ? -INFINITY : v4.x;
        va[1][i] = pad ? -INFINITY : v4.y;
        va[2][i] = pad ? -INFINITY : v4.z;
        va[3][i] = pad ? -INFINITY : v4.w;
    }
    // Pin: values opaque -> loads cannot be rematerialized (round-5 proven).
    #pragma unroll
    for (int i = 0; i < NPL; ++i)
        asm volatile("" : "+v"(va[0][i]), "+v"(va[1][i]),
                          "+v"(va[2][i]), "+v"(va[3][i]));

    // ---- Argmax per pixel (strict > => first index, jnp.argmax ties) ----
    float m[4]; int mi[4];
    #pragma unroll
    for (int j = 0; j < 4; ++j) { m[j] = va[j][0]; mi[j] = base_pl; }
    #pragma unroll
    for (int i = 1; i < NPL; ++i)
        #pragma unroll
        for (int j = 0; j < 4; ++j)
            if (va[j][i] > m[j]) { m[j] = va[j][i]; mi[j] = base_pl + i; }
    // combine the 4 plane-groups (lanes l, l^16, l^32, l^48 share pixels)
    #pragma unroll
    for (int j = 0; j < 4; ++j) {
        float om = __shfl_xor(m[j], 16); int oi = __shfl_xor(mi[j], 16);
        if (om > m[j] || (om == m[j] && oi < mi[j])) { m[j] = om; mi[j] = oi; }
        om = __shfl_xor(m[j], 32); oi = __shfl_xor(mi[j], 32);
        if (om > m[j] || (om == m[j] && oi < mi[j])) { m[j] = om; mi[j] = oi; }
    }
    int ui[4], vi[4];
    #pragma unroll
    for (int j = 0; j < 4; ++j) {
        ui[j] = (mi[j] * 158) >> 11;            // == mi/13 for mi in [0,169)
        vi[j] = mi[j] - ui[j] * Vdim;
    }

    // ---- Masked exp sums, all from registers ----
    float s[4]  = {0.f, 0.f, 0.f, 0.f};
    float su[4] = {0.f, 0.f, 0.f, 0.f};
    float sv[4] = {0.f, 0.f, 0.f, 0.f};
    int u = 3 * q, v = 4 * q;                   // base_pl/13, base_pl%13
    #pragma unroll
    for (int i = 0; i < NPL; ++i) {
        float du = (float)(u - 6), dv = (float)(v - 6);
        #pragma unroll
        for (int j = 0; j < 4; ++j) {
            bool in = ((unsigned)(u - ui[j] + 4) <= 8u) &&
                      ((unsigned)(v - vi[j] + 4) <= 8u);
            float e = in ? __expf(va[j][i] - m[j]) : 0.f;  // pad: -inf -> 0
            s[j]  += e;
            su[j] += e * du;
            sv[j] += e * dv;
        }
        if (++v == Vdim) { v = 0; ++u; }
    }
    #pragma unroll
    for (int j = 0; j < 4; ++j) {
        s[j]  += __shfl_xor(s[j], 16);  s[j]  += __shfl_xor(s[j], 32);
        su[j] += __shfl_xor(su[j], 16); su[j] += __shfl_xor(su[j], 32);
        sv[j] += __shfl_xor(sv[j], 16); sv[j] += __shfl_xor(sv[j], 32);
    }

    // ---- Group 0 writes both planes (256B contiguous float4 stores) ----
    if (q == 0) {
        float4 oU, oV;
        oU.x = su[0] / s[0]; oU.y = su[1] / s[1];
        oU.z = su[2] / s[2]; oU.w = su[3] / s[3];
        oV.x = sv[0] / s[0]; oV.y = sv[1] / s[1];
        oV.z = sv[2] / s[2]; oV.w = sv[3] / s[3];
        float* ob = out + (size_t)b * 2 * HW + hw;
        *(float4*)ob        = oU;               // flowU
        *(float4*)(ob + HW) = oV;               // flowV
    }
}

extern "C" void kernel_launch(void* const* d_in, const int* in_sizes, int n_in,
                              void* d_out, int out_size, void* d_ws, size_t ws_size,
                              hipStream_t stream) {
    const float* x = (const float*)d_in[0];
    float* out = (float*)d_out;
    flow_regression_kernel<<<NPIX / 256, 256, 0, stream>>>(x, out);
}

// Round 7
// 159.304 us; speedup vs baseline: 1.4347x; 1.4347x over previous
//
#include <hip/hip_runtime.h>
#include <math.h>

#define Vdim 13
#define HW 20480               // 128*160
#define UV 169
#define TRUNC 4
#define NPIX (8 * HW)          // 163840
#define PPB 64                 // pixels per block

typedef const __attribute__((address_space(1))) void glb_void;
typedef __attribute__((address_space(3))) void lds_void;

// R7: width-16 global_load_lds staging (4 planes = 1KB per instruction,
// 43 instrs/block vs R4's 169 width-4 instrs), unpadded plane-major LDS
// (256B/plane — required by the wave-uniform-base+lane*16 dest rule).
// Compute: 4 threads/pixel from LDS, shuffle-combine (R4's proven logic).
// Known cost: 4-way LDS bank conflict on compute reads (bank = pcol%32
// for all planes) ~1.58x on the LDS pipe — overlapped with VMEM/VALU.
__global__ __launch_bounds__(256) void flow_regression_kernel(
    const float* __restrict__ x, float* __restrict__ out) {
    __shared__ float lds[172 * 64];          // 44,032 B -> 3 blocks/CU

    int t    = threadIdx.x;
    int wave = t >> 6;
    int lane = t & 63;
    int pix0 = blockIdx.x * PPB;             // HW%64==0 -> b uniform per block
    int b    = pix0 / HW;
    int hw0  = pix0 - b * HW;
    const float* gbase = x + (size_t)b * UV * HW + hw0;

    // ---- Async stage: instr j moves planes 4j..4j+3 (1KB) into LDS.
    // lane L: global = plane (4j + L>>4), pixels (L&15)*4..+3 (16B);
    // LDS dest = base(j*1KB) + L*16 (wave-uniform base, lane-contiguous).
    {
        int pg = lane >> 4;                  // which of the 4 planes
        int px = (lane & 15) << 2;           // pixel-quad start
        for (int j = wave; j < 43; j += 4) { // waves 0-2: 11 instrs, wave 3: 10
            int pl = 4 * j + pg;
            pl = (pl > 168) ? 168 : pl;      // j==42 tail: dup plane 168 (slots 169-171 unused)
            const float* gp = gbase + (size_t)pl * HW + px;
            float* lp = (float*)&lds[j * 256];
            __builtin_amdgcn_global_load_lds((glb_void*)gp, (lds_void*)lp, 16, 0, 0);
        }
    }
    __builtin_amdgcn_s_waitcnt(0);           // drain my wave's async LDS stores
    __syncthreads();

    int q    = lane >> 4;                    // plane-group 0..3
    int pcol = (wave << 4) | (lane & 15);    // local pixel 0..63
    int base_pl = q * 43;                    // groups: 43,43,43,40 planes
    int npl     = (q == 3) ? 40 : 43;

    // ---- Pass 1: argmax (strict > => first index on ties) ----
    float m = -INFINITY;
    int mi = base_pl;
    #pragma unroll
    for (int i = 0; i < 43; ++i) {
        if (i < npl) {
            float v = lds[(base_pl + i) * 64 + pcol];
            if (v > m) { m = v; mi = base_pl + i; }
        }
    }
    {   // combine over the 4 groups (lanes l, l^16, l^32, l^48 share a pixel)
        float om = __shfl_xor(m, 16); int oi = __shfl_xor(mi, 16);
        if (om > m || (om == m && oi < mi)) { m = om; mi = oi; }
        om = __shfl_xor(m, 32); oi = __shfl_xor(mi, 32);
        if (om > m || (om == m && oi < mi)) { m = om; mi = oi; }
    }
    int ui = mi / Vdim;
    int vi = mi - ui * Vdim;

    // ---- Pass 2: masked exp sums from LDS ----
    float s = 0.f, su = 0.f, sv = 0.f;
    int u = base_pl / Vdim;
    int v = base_pl - u * Vdim;              // (0,0) (3,4) (6,8) (9,12)
    #pragma unroll
    for (int i = 0; i < 43; ++i) {
        if (i < npl) {
            float val = lds[(base_pl + i) * 64 + pcol];
            bool in = ((unsigned)(u - ui + TRUNC) <= 2u * TRUNC) &&
                      ((unsigned)(v - vi + TRUNC) <= 2u * TRUNC);
            float e = in ? __expf(val - m) : 0.f;
            s  += e;
            su += e * (float)(u - 6);
            sv += e * (float)(v - 6);
        }
        if (++v == Vdim) { v = 0; ++u; }
    }
    s  += __shfl_xor(s, 16);  su += __shfl_xor(su, 16);  sv += __shfl_xor(sv, 16);
    s  += __shfl_xor(s, 32);  su += __shfl_xor(su, 32);  sv += __shfl_xor(sv, 32);

    if (q == 0) {
        float inv = 1.0f / s;
        float* ob = out + (size_t)b * 2 * HW + (hw0 + pcol);
        ob[0]  = su * inv;   // flowU
        ob[HW] = sv * inv;   // flowV
    }
}

extern "C" void kernel_launch(void* const* d_in, const int* in_sizes, int n_in,
                              void* d_out, int out_size, void* d_ws, size_t ws_size,
                              hipStream_t stream) {
    const float* x = (const float*)d_in[0];
    float* out = (float*)d_out;
    flow_regression_kernel<<<NPIX / PPB, 256, 0, stream>>>(x, out);
}